// Round 3
// baseline (19994.821 us; speedup 1.0000x reference)
//
#include <hip/hip_runtime.h>
#include <hip/hip_bf16.h>

// NeuralODE Bosh3 fixed-step integrator, persistent-block formulation.
// Round 3: Btile=32 (64 blocks x 1024 thr, 2 row-panels x 8 waves),
// non-temporal output stores (kill L2 thrash), explicit 8-deep weight
// fragment prefetch into registers.

#define B_ 2048
#define L_ 128
#define P_ 8
#define W_ 512
#define T_ 128
#define BT_ 32                 // batch rows per block
#define NBLK (B_/BT_)          // 64 blocks

typedef __attribute__((ext_vector_type(8))) short short8;
typedef __attribute__((ext_vector_type(4))) float f32x4;

// packed weight sizes (ushort elements)
#define W0P_ELEMS (32*5*64*8)    // N=512 (32 nt), Kpad=160 (5 kt)
#define W1P_ELEMS (32*16*64*8)   // N=512, K=512 (16 kt)
#define W2P_ELEMS (8*16*64*8)    // N=128 (8 nt), K=512
#define W1P_OFF (W0P_ELEMS)
#define W2P_OFF (W0P_ELEMS + W1P_ELEMS)
#define WTOT (W0P_ELEMS + W1P_ELEMS + W2P_ELEMS)   // 409600 ushorts = 819200 B

__device__ __forceinline__ unsigned short f2bf(float f){
  unsigned u = __builtin_bit_cast(unsigned, f);
  u += 0x7fffu + ((u >> 16) & 1u);          // round-to-nearest-even
  return (unsigned short)(u >> 16);
}

__device__ __forceinline__ float tanh_fast(float x){
  float e = __expf(2.0f * x);
  return 1.0f - __fdividef(2.0f, e + 1.0f); // exact at saturation (+-1)
}

// Pack W[n][k] (row-major fp32) into MFMA B-fragments:
// dst[((nt*KT + kt)*64 + lane)*8 + j] = bf16(W[nt*16+(lane&15)][kt*32+(lane>>4)*8+j])
// idx in [WTOT, WTOT+T_-1): dts[idx-WTOT] = ts[i+1]-ts[i] (fp32) at wp+WTOT.
__global__ void prep_weights(const float* __restrict__ W0,
                             const float* __restrict__ W1,
                             const float* __restrict__ W2,
                             const float* __restrict__ ts,
                             unsigned short* __restrict__ wp){
  int idx = blockIdx.x * blockDim.x + threadIdx.x;
  if (idx >= WTOT){
    int t = idx - WTOT;
    if (t < T_ - 1){
      float* dts = (float*)(wp + WTOT);
      dts[t] = ts[t+1] - ts[t];
    }
    return;
  }
  const float* src; int base, KT, Korig;
  if (idx < W1P_OFF)      { src = W0; base = 0;       KT = 5;  Korig = 136; }
  else if (idx < W2P_OFF) { src = W1; base = W1P_OFF; KT = 16; Korig = 512; }
  else                    { src = W2; base = W2P_OFF; KT = 16; Korig = 512; }
  int e    = idx - base;
  int j    = e & 7;
  int frag = e >> 3;
  int lane = frag & 63;
  int tile = frag >> 6;
  int kt   = tile % KT;
  int nt   = tile / KT;
  int row  = nt*16 + (lane & 15);
  int k    = kt*32 + ((lane >> 4) << 3) + j;
  float v  = (k < Korig) ? src[row*Korig + k] : 0.0f;
  wp[idx] = f2bf(v);
}

// LDS layouts (bf16, XOR-swizzled: byte ^= (row&7)<<4 within the row).
#define XROWB 384    // x: 192 ushorts/row (0..127 y, 128..135 args, rest 0)
#define HROWB 1024   // h: 512 ushorts/row

__global__ __launch_bounds__(1024)
void ode_main(const float* __restrict__ x0,
              const float* __restrict__ args,
              const float* __restrict__ b0, const float* __restrict__ b1,
              const float* __restrict__ b2,
              const unsigned short* __restrict__ wp,
              float* __restrict__ out){
  __shared__ __align__(16) unsigned short xb[BT_*(XROWB/2)];   // 12 KiB
  __shared__ __align__(16) unsigned short h1[BT_*(HROWB/2)];   // 32 KiB
  __shared__ __align__(16) unsigned short h2[BT_*(HROWB/2)];   // 32 KiB

  const int tid  = threadIdx.x;
  const int lane = tid & 63;
  const int wv   = tid >> 6;     // wave 0..15
  const int p    = wv >> 3;      // row-panel 0..1
  const int w    = wv & 7;       // N-split wave 0..7
  const int lo   = lane & 15;
  const int hi   = lane >> 4;    // 0..3
  const int p16  = p*16;
  const int r0   = blockIdx.x * BT_;

  const unsigned short* w0p = wp;
  const unsigned short* w1p = wp + W1P_OFF;
  const unsigned short* w2p = wp + W2P_OFF;
  const float* dts = (const float*)(wp + WTOT);

  // zero x buffer (zeroes are swizzle-invariant)
  for (int i = tid; i < BT_*(XROWB/2); i += 1024) xb[i] = 0;
  __syncthreads();

  // args -> x cols 128..135 (constant across all steps)
  if (tid < BT_*P_){
    int r = tid >> 3, pp = tid & 7;
    unsigned short v = f2bf(args[(r0 + r)*P_ + pp]);
    *(unsigned short*)((char*)xb + r*XROWB + (((128 + pp)*2) ^ ((r & 7) << 4))) = v;
  }

  // per-wave A-read bases (row = p16+lo), swizzle keyed by lo
  const char* xa  = (const char*)xb + (p16+lo)*XROWB;
  const char* h1a = (const char*)h1 + (p16+lo)*HROWB;
  const char* h2a = (const char*)h2 + (p16+lo)*HROWB;
  const int aswz  = (lo & 7) << 4;

  // per-thread write bases (rows p16+4hi+j)
  char* h1w[4]; char* h2w[4]; char* xbw[4]; int wswz[4];
  #pragma unroll
  for (int j = 0; j < 4; ++j){
    int rj = 4*hi + j;
    h1w[j] = (char*)h1 + (p16+rj)*HROWB;
    h2w[j] = (char*)h2 + (p16+rj)*HROWB;
    xbw[j] = (char*)xb + (p16+rj)*XROWB;
    wswz[j] = (rj & 7) << 4;
  }

  // per-thread persistent ODE state: rows p16+4hi+j, col c3 = w*16+lo
  const int c3 = w*16 + lo;
  float yr[4], yn[4];
  float b2v = b2[c3];
  float b0v[4], b1v[4];
  #pragma unroll
  for (int i = 0; i < 4; ++i){
    b0v[i] = b0[(w + 8*i)*16 + lo];
    b1v[i] = b1[(w + 8*i)*16 + lo];
  }
  #pragma unroll
  for (int j = 0; j < 4; ++j){
    int row = p16 + 4*hi + j;
    float v = x0[(r0 + row)*L_ + c3];
    yr[j] = v;
    __builtin_nontemporal_store(v, &out[((r0 + row)*T_ + 0)*L_ + c3]);
    *(unsigned short*)(xbw[j] + ((c3*2) ^ wswz[j])) = f2bf(v);
  }

  // One vector-field eval: x(LDS) -> h1 -> h2 -> d (layer-3 accum, no bias)
  auto evalf = [&](f32x4& dout){
    // ---- layer 1: K=160 (5 kt), N=512; wave w owns nt = w+8i
    {
      short8 af[5];
      #pragma unroll
      for (int kt = 0; kt < 5; ++kt)
        af[kt] = *(const short8*)(xa + ((kt*64 + hi*16) ^ aswz));
      #pragma unroll
      for (int i = 0; i < 4; ++i){
        const unsigned short* wb = w0p + (((w+8*i)*5)*64 + lane)*8;
        short8 bf[5];
        #pragma unroll
        for (int q = 0; q < 5; ++q) bf[q] = *(const short8*)(wb + q*512);
        f32x4 acc = {0.f,0.f,0.f,0.f};
        #pragma unroll
        for (int q = 0; q < 5; ++q)
          acc = __builtin_amdgcn_mfma_f32_16x16x32_bf16(af[q], bf[q], acc, 0, 0, 0);
        #pragma unroll
        for (int j = 0; j < 4; ++j){
          float v = tanh_fast(acc[j] + b0v[i]);
          int col = (w+8*i)*16 + lo;
          *(unsigned short*)(h1w[j] + ((col*2) ^ wswz[j])) = f2bf(v);
        }
      }
    }
    __syncthreads();
    // ---- layer 2: K=512 (16 kt), N=512
    {
      f32x4 acc2[4];
      #pragma unroll
      for (int i = 0; i < 4; ++i) acc2[i] = f32x4{0.f,0.f,0.f,0.f};
      #pragma unroll
      for (int half = 0; half < 2; ++half){
        short8 af8[8];
        #pragma unroll
        for (int q = 0; q < 8; ++q)
          af8[q] = *(const short8*)(h1a + (((half*8+q)*64 + hi*16) ^ aswz));
        #pragma unroll
        for (int i = 0; i < 4; ++i){
          const unsigned short* wb = w1p + (((w+8*i)*16 + half*8)*64 + lane)*8;
          short8 bf[8];
          #pragma unroll
          for (int q = 0; q < 8; ++q) bf[q] = *(const short8*)(wb + q*512);
          #pragma unroll
          for (int q = 0; q < 8; ++q)
            acc2[i] = __builtin_amdgcn_mfma_f32_16x16x32_bf16(af8[q], bf[q], acc2[i], 0, 0, 0);
        }
      }
      #pragma unroll
      for (int i = 0; i < 4; ++i)
        #pragma unroll
        for (int j = 0; j < 4; ++j){
          float v = tanh_fast(acc2[i][j] + b1v[i]);
          int col = (w+8*i)*16 + lo;
          *(unsigned short*)(h2w[j] + ((col*2) ^ wswz[j])) = f2bf(v);
        }
    }
    __syncthreads();
    // ---- layer 3: K=512 (16 kt), N=128; wave w owns nt = w
    {
      f32x4 acc3 = {0.f,0.f,0.f,0.f};
      #pragma unroll
      for (int half = 0; half < 2; ++half){
        short8 af8[8];
        #pragma unroll
        for (int q = 0; q < 8; ++q)
          af8[q] = *(const short8*)(h2a + (((half*8+q)*64 + hi*16) ^ aswz));
        const unsigned short* wb = w2p + ((w*16 + half*8)*64 + lane)*8;
        short8 bf[8];
        #pragma unroll
        for (int q = 0; q < 8; ++q) bf[q] = *(const short8*)(wb + q*512);
        #pragma unroll
        for (int q = 0; q < 8; ++q)
          acc3 = __builtin_amdgcn_mfma_f32_16x16x32_bf16(af8[q], bf[q], acc3, 0, 0, 0);
      }
      dout = acc3;
    }
  };

  // Bosh3: k1=f(y); k2=f(y+dt/2 k1); k3=f(y+3dt/4 k2); y+=dt(2/9 k1+1/3 k2+4/9 k3)
  for (int t = 1; t < T_; ++t){
    float dt = dts[t-1];
    f32x4 d;

    __syncthreads();                       // xb ready
    evalf(d);                              // k1
    #pragma unroll
    for (int j = 0; j < 4; ++j){
      float k = d[j] + b2v;
      yn[j] = yr[j] + dt*(2.0f/9.0f)*k;
      float xs = yr[j] + 0.5f*dt*k;
      *(unsigned short*)(xbw[j] + ((c3*2) ^ wswz[j])) = f2bf(xs);
    }

    __syncthreads();
    evalf(d);                              // k2
    #pragma unroll
    for (int j = 0; j < 4; ++j){
      float k = d[j] + b2v;
      yn[j] += dt*(1.0f/3.0f)*k;
      float xs = yr[j] + 0.75f*dt*k;
      *(unsigned short*)(xbw[j] + ((c3*2) ^ wswz[j])) = f2bf(xs);
    }

    __syncthreads();
    evalf(d);                              // k3
    #pragma unroll
    for (int j = 0; j < 4; ++j){
      float k = d[j] + b2v;
      yn[j] += dt*(4.0f/9.0f)*k;
      yr[j] = yn[j];
      int row = p16 + 4*hi + j;
      __builtin_nontemporal_store(yr[j], &out[((r0 + row)*T_ + t)*L_ + c3]);
      *(unsigned short*)(xbw[j] + ((c3*2) ^ wswz[j])) = f2bf(yr[j]);
    }
  }
}

extern "C" void kernel_launch(void* const* d_in, const int* in_sizes, int n_in,
                              void* d_out, int out_size, void* d_ws, size_t ws_size,
                              hipStream_t stream) {
  const float* x0   = (const float*)d_in[0];
  const float* ts   = (const float*)d_in[1];
  const float* args = (const float*)d_in[2];
  const float* W0   = (const float*)d_in[3];
  const float* b0   = (const float*)d_in[4];
  const float* W1   = (const float*)d_in[5];
  const float* b1   = (const float*)d_in[6];
  const float* W2   = (const float*)d_in[7];
  const float* b2   = (const float*)d_in[8];
  unsigned short* wp = (unsigned short*)d_ws;   // 819,200 B weights + 512 B dts
  float* out = (float*)d_out;

  prep_weights<<<(WTOT + T_ + 255)/256, 256, 0, stream>>>(W0, W1, W2, ts, wp);
  ode_main<<<NBLK, 1024, 0, stream>>>(x0, args, b0, b1, b2, wp, out);
}

// Round 4
// 10094.810 us; speedup vs baseline: 1.9807x; 1.9807x over previous
//
#include <hip/hip_runtime.h>
#include <hip/hip_bf16.h>

// NeuralODE Bosh3 fixed-step integrator, persistent-block formulation.
// Round 4: Btile=16, 128 blocks x 1024 threads (16 waves, 4 waves/SIMD),
// explicit launch_bounds(1024,4) (VGPR cap 512 -- round 3 spilled at cap 64),
// cooperative full-line non-temporal output stores staged through LDS.

#define B_ 2048
#define L_ 128
#define P_ 8
#define W_ 512
#define T_ 128
#define BT_ 16
#define NBLK (B_/BT_)          // 128 blocks

typedef __attribute__((ext_vector_type(8))) short short8;
typedef __attribute__((ext_vector_type(4))) float f32x4;

// packed weight sizes (ushort elements)
#define W0P_ELEMS (32*5*64*8)    // N=512 (32 nt), Kpad=160 (5 kt)
#define W1P_ELEMS (32*16*64*8)   // N=512, K=512 (16 kt)
#define W2P_ELEMS (8*16*64*8)    // N=128 (8 nt), K=512
#define W1P_OFF (W0P_ELEMS)
#define W2P_OFF (W0P_ELEMS + W1P_ELEMS)
#define WTOT (W0P_ELEMS + W1P_ELEMS + W2P_ELEMS)   // 409600 ushorts = 819200 B

__device__ __forceinline__ unsigned short f2bf(float f){
  unsigned u = __builtin_bit_cast(unsigned, f);
  u += 0x7fffu + ((u >> 16) & 1u);          // round-to-nearest-even
  return (unsigned short)(u >> 16);
}

__device__ __forceinline__ float tanh_fast(float x){
  float e = __expf(2.0f * x);
  return 1.0f - __fdividef(2.0f, e + 1.0f); // exact at saturation (+-1)
}

// Pack W[n][k] (row-major fp32) into MFMA B-fragments:
// dst[((nt*KT + kt)*64 + lane)*8 + j] = bf16(W[nt*16+(lane&15)][kt*32+(lane>>4)*8+j])
// idx in [WTOT, WTOT+T_-1): dts[idx-WTOT] = ts[i+1]-ts[i] (fp32) at wp+WTOT.
__global__ void prep_weights(const float* __restrict__ W0,
                             const float* __restrict__ W1,
                             const float* __restrict__ W2,
                             const float* __restrict__ ts,
                             unsigned short* __restrict__ wp){
  int idx = blockIdx.x * blockDim.x + threadIdx.x;
  if (idx >= WTOT){
    int t = idx - WTOT;
    if (t < T_ - 1){
      float* dts = (float*)(wp + WTOT);
      dts[t] = ts[t+1] - ts[t];
    }
    return;
  }
  const float* src; int base, KT, Korig;
  if (idx < W1P_OFF)      { src = W0; base = 0;       KT = 5;  Korig = 136; }
  else if (idx < W2P_OFF) { src = W1; base = W1P_OFF; KT = 16; Korig = 512; }
  else                    { src = W2; base = W2P_OFF; KT = 16; Korig = 512; }
  int e    = idx - base;
  int j    = e & 7;
  int frag = e >> 3;
  int lane = frag & 63;
  int tile = frag >> 6;
  int kt   = tile % KT;
  int nt   = tile / KT;
  int row  = nt*16 + (lane & 15);
  int k    = kt*32 + ((lane >> 4) << 3) + j;
  float v  = (k < Korig) ? src[row*Korig + k] : 0.0f;
  wp[idx] = f2bf(v);
}

// LDS layouts (bf16, XOR-swizzled: byte ^= (row&7)<<4 within the row).
#define XROWB 384    // x: 192 ushorts/row (0..127 y, 128..135 args, rest 0)
#define HROWB 1024   // h: 512 ushorts/row

__global__ __launch_bounds__(1024, 4)
void ode_main(const float* __restrict__ x0,
              const float* __restrict__ args,
              const float* __restrict__ b0, const float* __restrict__ b1,
              const float* __restrict__ b2,
              const unsigned short* __restrict__ wp,
              float* __restrict__ out){
  __shared__ __align__(16) unsigned short xb[BT_*(XROWB/2)];   // 6 KiB
  __shared__ __align__(16) unsigned short h1[BT_*(HROWB/2)];   // 16 KiB
  __shared__ __align__(16) unsigned short h2[BT_*(HROWB/2)];   // 16 KiB
  __shared__ __align__(16) float ybuf[BT_][L_];                // 8 KiB fp32 state

  const int tid  = threadIdx.x;
  const int lane = tid & 63;
  const int wv   = tid >> 6;     // wave 0..15
  const int lo   = lane & 15;
  const int hi   = lane >> 4;    // 0..3
  const int r0   = blockIdx.x * BT_;
  const bool owner = (wv < 8);

  const unsigned short* w0p = wp;
  const unsigned short* w1p = wp + W1P_OFF;
  const unsigned short* w2p = wp + W2P_OFF;
  const float* dts = (const float*)(wp + WTOT);

  // zero x buffer (zeroes are swizzle-invariant)
  for (int i = tid; i < BT_*(XROWB/2); i += 1024) xb[i] = 0;
  __syncthreads();

  // args -> x cols 128..135 (constant across all steps)
  if (tid < BT_*P_){
    int r = tid >> 3, pp = tid & 7;
    unsigned short v = f2bf(args[(r0 + r)*P_ + pp]);
    *(unsigned short*)((char*)xb + r*XROWB + (((128 + pp)*2) ^ ((r & 7) << 4))) = v;
  }

  // per-wave A-read bases (row = lo), swizzle keyed by lo
  const char* xa  = (const char*)xb + lo*XROWB;
  const char* h1a = (const char*)h1 + lo*HROWB;
  const char* h2a = (const char*)h2 + lo*HROWB;
  const int aswz  = (lo & 7) << 4;

  // per-thread write bases (rows 4*hi+j)
  char* h1w[4]; char* h2w[4]; char* xbw[4]; int wswz[4];
  #pragma unroll
  for (int j = 0; j < 4; ++j){
    int rj = 4*hi + j;
    h1w[j] = (char*)h1 + rj*HROWB;
    h2w[j] = (char*)h2 + rj*HROWB;
    xbw[j] = (char*)xb + rj*XROWB;
    wswz[j] = (rj & 7) << 4;
  }

  // biases for this wave's N-tiles (nt = 2wv, 2wv+1 in layers 1/2)
  float b0v[2], b1v[2];
  #pragma unroll
  for (int i = 0; i < 2; ++i){
    b0v[i] = b0[(2*wv + i)*16 + lo];
    b1v[i] = b1[(2*wv + i)*16 + lo];
  }

  // ODE state: owners (wv<8) hold rows 4hi+j, col c3 = wv*16+lo
  const int c3 = (wv & 7)*16 + lo;
  float yr[4], yn[4];
  float b2v = owner ? b2[c3] : 0.0f;
  if (owner){
    #pragma unroll
    for (int j = 0; j < 4; ++j){
      int row = 4*hi + j;
      float v = x0[(r0 + row)*L_ + c3];
      yr[j] = v;
      ybuf[row][c3] = v;
      *(unsigned short*)(xbw[j] + ((c3*2) ^ wswz[j])) = f2bf(v);
    }
  }

  // One vector-field eval: x(LDS) -> h1 -> h2 -> d (layer-3 accum, no bias)
  auto evalf = [&](f32x4& dout){
    // ---- layer 1: K=160 (5 kt), N=512; wave wv owns nt = 2wv, 2wv+1
    {
      short8 af[5];
      #pragma unroll
      for (int kt = 0; kt < 5; ++kt)
        af[kt] = *(const short8*)(xa + ((kt*64 + hi*16) ^ aswz));
      #pragma unroll
      for (int i = 0; i < 2; ++i){
        int nt = 2*wv + i;
        const unsigned short* wb = w0p + (nt*5*64 + lane)*8;
        short8 bf[5];
        #pragma unroll
        for (int q = 0; q < 5; ++q) bf[q] = *(const short8*)(wb + q*512);
        f32x4 acc = {0.f,0.f,0.f,0.f};
        #pragma unroll
        for (int q = 0; q < 5; ++q)
          acc = __builtin_amdgcn_mfma_f32_16x16x32_bf16(af[q], bf[q], acc, 0, 0, 0);
        #pragma unroll
        for (int j = 0; j < 4; ++j){
          float v = tanh_fast(acc[j] + b0v[i]);
          int col = nt*16 + lo;
          *(unsigned short*)(h1w[j] + ((col*2) ^ wswz[j])) = f2bf(v);
        }
      }
    }
    __syncthreads();
    // ---- layer 2: K=512 (16 kt), N=512; nt = 2wv, 2wv+1
    {
      f32x4 acc2[2];
      acc2[0] = f32x4{0.f,0.f,0.f,0.f};
      acc2[1] = f32x4{0.f,0.f,0.f,0.f};
      #pragma unroll
      for (int half = 0; half < 2; ++half){
        short8 af8[8];
        #pragma unroll
        for (int q = 0; q < 8; ++q)
          af8[q] = *(const short8*)(h1a + (((half*8+q)*64 + hi*16) ^ aswz));
        #pragma unroll
        for (int i = 0; i < 2; ++i){
          const unsigned short* wb = w1p + (((2*wv+i)*16 + half*8)*64 + lane)*8;
          short8 bf[8];
          #pragma unroll
          for (int q = 0; q < 8; ++q) bf[q] = *(const short8*)(wb + q*512);
          #pragma unroll
          for (int q = 0; q < 8; ++q)
            acc2[i] = __builtin_amdgcn_mfma_f32_16x16x32_bf16(af8[q], bf[q], acc2[i], 0, 0, 0);
        }
      }
      #pragma unroll
      for (int i = 0; i < 2; ++i)
        #pragma unroll
        for (int j = 0; j < 4; ++j){
          float v = tanh_fast(acc2[i][j] + b1v[i]);
          int col = (2*wv+i)*16 + lo;
          *(unsigned short*)(h2w[j] + ((col*2) ^ wswz[j])) = f2bf(v);
        }
    }
    __syncthreads();
    // ---- layer 3: K=512 (16 kt), N=128; waves 0..7 own nt = wv
    if (owner){
      f32x4 acc3 = {0.f,0.f,0.f,0.f};
      #pragma unroll
      for (int half = 0; half < 2; ++half){
        short8 af8[8];
        #pragma unroll
        for (int q = 0; q < 8; ++q)
          af8[q] = *(const short8*)(h2a + (((half*8+q)*64 + hi*16) ^ aswz));
        const unsigned short* wb = w2p + ((wv*16 + half*8)*64 + lane)*8;
        short8 bf[8];
        #pragma unroll
        for (int q = 0; q < 8; ++q) bf[q] = *(const short8*)(wb + q*512);
        #pragma unroll
        for (int q = 0; q < 8; ++q)
          acc3 = __builtin_amdgcn_mfma_f32_16x16x32_bf16(af8[q], bf[q], acc3, 0, 0, 0);
      }
      dout = acc3;
    }
  };

  // Bosh3 loop. ybuf holds y_{t-1}; cooperative nt-store overlaps with k1.
  for (int t = 1; t < T_; ++t){
    float dt = dts[t-1];
    f32x4 d;

    __syncthreads();                       // xb + ybuf ready
    // cooperative full-line nt store of y_{t-1} (overlaps with k1 below)
    if (tid < 512){
      int row = tid >> 5, c4 = (tid & 31) << 2;
      f32x4 v = *(const f32x4*)&ybuf[row][c4];
      __builtin_nontemporal_store(v, (f32x4*)&out[((r0 + row)*T_ + (t-1))*L_ + c4]);
    }

    evalf(d);                              // k1
    if (owner){
      #pragma unroll
      for (int j = 0; j < 4; ++j){
        float k = d[j] + b2v;
        yn[j] = yr[j] + dt*(2.0f/9.0f)*k;
        float xs = yr[j] + 0.5f*dt*k;
        *(unsigned short*)(xbw[j] + ((c3*2) ^ wswz[j])) = f2bf(xs);
      }
    }

    __syncthreads();
    evalf(d);                              // k2
    if (owner){
      #pragma unroll
      for (int j = 0; j < 4; ++j){
        float k = d[j] + b2v;
        yn[j] += dt*(1.0f/3.0f)*k;
        float xs = yr[j] + 0.75f*dt*k;
        *(unsigned short*)(xbw[j] + ((c3*2) ^ wswz[j])) = f2bf(xs);
      }
    }

    __syncthreads();
    evalf(d);                              // k3
    if (owner){
      #pragma unroll
      for (int j = 0; j < 4; ++j){
        float k = d[j] + b2v;
        yn[j] += dt*(4.0f/9.0f)*k;
        yr[j] = yn[j];
        int row = 4*hi + j;
        ybuf[row][c3] = yr[j];
        *(unsigned short*)(xbw[j] + ((c3*2) ^ wswz[j])) = f2bf(yr[j]);
      }
    }
  }

  // final slice t = T_-1
  __syncthreads();
  if (tid < 512){
    int row = tid >> 5, c4 = (tid & 31) << 2;
    f32x4 v = *(const f32x4*)&ybuf[row][c4];
    __builtin_nontemporal_store(v, (f32x4*)&out[((r0 + row)*T_ + (T_-1))*L_ + c4]);
  }
}

extern "C" void kernel_launch(void* const* d_in, const int* in_sizes, int n_in,
                              void* d_out, int out_size, void* d_ws, size_t ws_size,
                              hipStream_t stream) {
  const float* x0   = (const float*)d_in[0];
  const float* ts   = (const float*)d_in[1];
  const float* args = (const float*)d_in[2];
  const float* W0   = (const float*)d_in[3];
  const float* b0   = (const float*)d_in[4];
  const float* W1   = (const float*)d_in[5];
  const float* b1   = (const float*)d_in[6];
  const float* W2   = (const float*)d_in[7];
  const float* b2   = (const float*)d_in[8];
  unsigned short* wp = (unsigned short*)d_ws;   // 819,200 B weights + 512 B dts
  float* out = (float*)d_out;

  prep_weights<<<(WTOT + T_ + 255)/256, 256, 0, stream>>>(W0, W1, W2, ts, wp);
  ode_main<<<NBLK, 1024, 0, stream>>>(x0, args, b0, b1, b2, wp, out);
}